// Round 11
// baseline (404.000 us; speedup 1.0000x reference)
//
#include <hip/hip_runtime.h>

#define N_NODES 100000
#define N_EDGES 600000
#define DIM 128
#define SCAN_B 1024
#define NCHUNK 98   // ceil(100000/1024)

typedef __attribute__((ext_vector_type(4))) float f32x4;
typedef __attribute__((ext_vector_type(8))) short bf16x8;
typedef __attribute__((ext_vector_type(4))) unsigned short u16x4;
typedef __attribute__((ext_vector_type(8))) unsigned short u16x8;

__device__ __forceinline__ unsigned short f2bf(float f) {
    union { float f; unsigned u; } cv; cv.f = f;
    unsigned r = (cv.u + 0x7FFFu + ((cv.u >> 16) & 1u)) >> 16;
    return (unsigned short)r;
}
__device__ __forceinline__ float bf2f(unsigned short v) {
    union { unsigned u; float f; } c; c.u = ((unsigned)v) << 16; return c.f;
}

// ---------------- setup: degree / scan / csr fill / weight+x prep ----------------

__global__ void k_degree(const int* __restrict__ src, int* __restrict__ degi) {
    int e = blockIdx.x * 256 + threadIdx.x;
    if (e < N_EDGES) atomicAdd(&degi[src[e]], 1);
}

__global__ void k_chunksum(const int* __restrict__ degi, int* __restrict__ bsum) {
    __shared__ int sm[SCAN_B];
    int i = blockIdx.x * SCAN_B + threadIdx.x;
    sm[threadIdx.x] = (i < N_NODES) ? degi[i] : 0;
    __syncthreads();
    for (int s = SCAN_B / 2; s > 0; s >>= 1) {
        if (threadIdx.x < (unsigned)s) sm[threadIdx.x] += sm[threadIdx.x + s];
        __syncthreads();
    }
    if (threadIdx.x == 0) bsum[blockIdx.x] = sm[0];
}

// rowptr with FUSED chunk-prefix: each block reduces bsum[0..bid-1] itself (98 ints).
__global__ void k_rowptr(const int* __restrict__ degi, const int* __restrict__ bsum,
                         int* __restrict__ rowptr, int* __restrict__ cnt,
                         float* __restrict__ inv0, float* __restrict__ inv1,
                         float* __restrict__ inv2) {
    __shared__ int sm[SCAN_B];
    __shared__ int sb[128];
    int i = blockIdx.x * SCAN_B + threadIdx.x;
    int v = (i < N_NODES) ? degi[i] : 0;
    sm[threadIdx.x] = v;
    if (threadIdx.x < 128)
        sb[threadIdx.x] = (threadIdx.x < blockIdx.x) ? bsum[threadIdx.x] : 0;
    __syncthreads();
    for (int s = 1; s < SCAN_B; s <<= 1) {
        int a = (threadIdx.x >= (unsigned)s) ? sm[threadIdx.x - s] : 0;
        __syncthreads();
        sm[threadIdx.x] += a;
        __syncthreads();
    }
    for (int s = 64; s > 0; s >>= 1) {
        if (threadIdx.x < (unsigned)s) sb[threadIdx.x] += sb[threadIdx.x + s];
        __syncthreads();
    }
    if (i < N_NODES) {
        int excl = sb[0] + sm[threadIdx.x] - v;
        rowptr[i] = excl;
        cnt[i] = excl;
        float d = (float)v;
        inv0[i] = (v > 0) ? 1.0f / d : 0.0f;
        inv1[i] = 1.0f / (d + 1.0f);
        inv2[i] = 1.0f / (d + 2.0f);
    }
}

__global__ void k_fill(const int* __restrict__ src, const int* __restrict__ dst,
                       int* __restrict__ cnt, int* __restrict__ col) {
    int e = blockIdx.x * 256 + threadIdx.x;
    if (e < N_EDGES) {
        int pos = atomicAdd(&cnt[src[e]], 1);
        col[pos] = dst[e];
    }
}

// Merged prep: blocks [0,768) pack W -> Wp; blocks [768,13268) cast x -> bf16 xb.
// Wpack[l][kb(8)][nt(16)][lane(64)][j(8)] = W[k][n], k=kb*32+(lane>>4)*8+j, n=nt*16+(lane&15)
__global__ void k_prep(const float* __restrict__ G1, const float* __restrict__ G2,
                       const float* __restrict__ B1, const float* __restrict__ B2,
                       short* __restrict__ Wp,
                       const float* __restrict__ x, unsigned short* __restrict__ xb) {
    if (blockIdx.x < 768) {
        int idx = blockIdx.x * 256 + threadIdx.x;  // 3*65536 = 196608 total
        int j = idx & 7, lane = (idx >> 3) & 63, nt = (idx >> 9) & 15, kb = (idx >> 13) & 7, l = idx >> 16;
        int k = kb * 32 + (lane >> 4) * 8 + j;
        int n = nt * 16 + (lane & 15);
        float v;
        if (n < 128) {
            v = (k < 128) ? G1[(l * 128 + n) * 128 + k] : G2[(l * 128 + n) * 128 + (k - 128)];
        } else {
            int n2 = n - 128;
            v = (k < 128) ? B1[(l * 128 + n2) * 128 + k] : B2[(l * 128 + n2) * 128 + (k - 128)];
        }
        Wp[idx] = (short)f2bf(v);
    } else {
        int i = ((blockIdx.x - 768) * 256 + threadIdx.x) * 4;
        f32x4 v = *(const f32x4*)(x + i);
        unsigned short o0 = f2bf(v[0]), o1 = f2bf(v[1]), o2 = f2bf(v[2]), o3 = f2bf(v[3]);
        unsigned long long pk = (unsigned long long)o0 | ((unsigned long long)o1 << 16)
                              | ((unsigned long long)o2 << 32) | ((unsigned long long)o3 << 48);
        *(unsigned long long*)(xb + i) = pk;
    }
}

// ---------------- gathers ----------------
// lane = g*16 + c: sub-row g handles its row; c indexes 8-bf16 (16B) chunks.
// Loads batched-issued unconditionally (oob lanes read row 0), accumulate predicated.
// The multi-operand opaque asm holds the whole batch simultaneously live -> one
// vmcnt round trip per batch (R10: VGPR=68 confirmed the batch stays live).

template <int NE>
__device__ __forceinline__ void gath_issue(const u16x8* __restrict__ h8,
        int idx, int base, int c, int d, float* acc) {
    u16x8 v[NE];
#pragma unroll
    for (int e = 0; e < NE; ++e) {
        int ce = __shfl(idx, base + e, 64);
        v[e] = h8[(size_t)ce * 16 + c];
    }
    if constexpr (NE == 8) {
        asm volatile("" : "+v"(v[0]), "+v"(v[1]), "+v"(v[2]), "+v"(v[3]),
                          "+v"(v[4]), "+v"(v[5]), "+v"(v[6]), "+v"(v[7]));
    } else {
        asm volatile("" : "+v"(v[0]), "+v"(v[1]), "+v"(v[2]), "+v"(v[3]),
                          "+v"(v[4]), "+v"(v[5]), "+v"(v[6]), "+v"(v[7]),
                          "+v"(v[8]), "+v"(v[9]), "+v"(v[10]), "+v"(v[11]),
                          "+v"(v[12]), "+v"(v[13]), "+v"(v[14]), "+v"(v[15]));
    }
#pragma unroll
    for (int e = 0; e < NE; ++e) {
        if (e < d) {
#pragma unroll
            for (int j = 0; j < 8; ++j) acc[j] += bf2f(v[e][j]);
        }
    }
}

__device__ __forceinline__ void gather4(const u16x8* __restrict__ h8,
        const int* __restrict__ col, int start, int d, int lane, float* acc) {
    int c = lane & 15;
    int base = lane & 48;
    int dd = d < 16 ? d : 16;
    int idx = (c < dd) ? col[start + c] : 0;
    int dm = d;
    int tmx = __shfl_xor(dm, 16);
    dm = dm > tmx ? dm : tmx;
    tmx = __shfl_xor(dm, 32);
    dm = dm > tmx ? dm : tmx;
    if (dm <= 8) {
        gath_issue<8>(h8, idx, base, c, d, acc);
    } else {
        gath_issue<16>(h8, idx, base, c, d, acc);
        if (dm > 16) {
            for (int e = 16; e < d; ++e) {
                int c0 = col[start + e];
                u16x8 v = h8[(size_t)c0 * 16 + c];
#pragma unroll
                for (int j = 0; j < 8; ++j) acc[j] += bf2f(v[j]);
            }
        }
    }
}

// Combined super-row gather: st row = 512B = [tail 16 chunks | head 16 chunks].
template <int NE>
__device__ __forceinline__ void gath_issue2c(const u16x8* __restrict__ st8,
        int idx, int base, int c, int d, int e0, float* accT, float* accH) {
    u16x8 vT[NE], vH[NE];
#pragma unroll
    for (int e = 0; e < NE; ++e) {
        int ce = __shfl(idx, base + e0 + e, 64);
        size_t b = (size_t)ce * 32 + c;
        vT[e] = st8[b];
        vH[e] = st8[b + 16];
    }
    static_assert(NE == 8, "pin written for NE=8");
    asm volatile("" : "+v"(vT[0]), "+v"(vT[1]), "+v"(vT[2]), "+v"(vT[3]),
                      "+v"(vT[4]), "+v"(vT[5]), "+v"(vT[6]), "+v"(vT[7]),
                      "+v"(vH[0]), "+v"(vH[1]), "+v"(vH[2]), "+v"(vH[3]),
                      "+v"(vH[4]), "+v"(vH[5]), "+v"(vH[6]), "+v"(vH[7]));
#pragma unroll
    for (int e = 0; e < NE; ++e) {
        if (e0 + e < d) {
#pragma unroll
            for (int j = 0; j < 8; ++j) {
                accT[j] += bf2f(vT[e][j]);
                accH[j] += bf2f(vH[e][j]);
            }
        }
    }
}

__device__ __forceinline__ void gather4_dualc(const u16x8* __restrict__ st8,
        const int* __restrict__ col, int start, int d, int lane,
        float* accT, float* accH) {
    int c = lane & 15;
    int base = lane & 48;
    int dd = d < 16 ? d : 16;
    int idx = (c < dd) ? col[start + c] : 0;
    int dm = d;
    int tmx = __shfl_xor(dm, 16);
    dm = dm > tmx ? dm : tmx;
    tmx = __shfl_xor(dm, 32);
    dm = dm > tmx ? dm : tmx;
    if (dm <= 8) {
        gath_issue2c<8>(st8, idx, base, c, d, 0, accT, accH);
    } else {
        gath_issue2c<8>(st8, idx, base, c, d, 0, accT, accH);
        gath_issue2c<8>(st8, idx, base, c, d, 8, accT, accH);
        if (dm > 16) {
            for (int e = 16; e < d; ++e) {
                int c0 = col[start + e];
                size_t b = (size_t)c0 * 32 + c;
                u16x8 vT = st8[b];
                u16x8 vH = st8[b + 16];
#pragma unroll
                for (int j = 0; j < 8; ++j) {
                    accT[j] += bf2f(vT[j]);
                    accH[j] += bf2f(vH[j]);
                }
            }
        }
    }
}

// ---------------- tail GEMM phase, 32 rows per block ----------------
// Z = [h | inv0*S] @ Wl (256 cols), A from LDS, B from L1-hot Wp: wave w owns nt pairs
// {2w,2w+1} and {2w+8,2w+9}; each B fragment feeds both A-tiles.
// Epilogue output staged IN-PLACE into sH (bijective (row,col)<->thread map; barrier
// after the MFMA loop guarantees all ds_reads of sH complete before overwrite).
// m = h + gamma*R + beta - inv0*S;  h_new = inv2*(S + h + m)
// last: emb = 0.25*(x+t1+t2+t3) -> out rows with deg<=5 only (t1 = st1 tail half).
__device__ __forceinline__ void tail_gemm32(
    int rb,
    unsigned short (*sH)[136], unsigned short (*sS)[136],
    unsigned short* __restrict__ stn,       // combined next-state (tail half written here)
    const unsigned short* __restrict__ st1, // combined layer-1 state (t1 in tail half)
    const unsigned short* __restrict__ xb,
    float* __restrict__ outp,
    const float* __restrict__ Rl, const short* __restrict__ Wp,
    const float* __restrict__ inv0, const float* __restrict__ inv2,
    const int* __restrict__ degi, int last)
{
    int wave = threadIdx.x >> 6, lane = threadIdx.x & 63;
    int q = lane >> 4, m = lane & 15;
    float w0a = inv0[rb + m], w0b = inv0[rb + 16 + m];
    const short* wl = Wp + lane * 8;

    const f32x4 vz = {0.f, 0.f, 0.f, 0.f};
    f32x4 aA[2][2] = {{vz, vz}, {vz, vz}}, aB[2][2] = {{vz, vz}, {vz, vz}};

#pragma unroll
    for (int kb = 0; kb < 4; ++kb) {              // h-half of K
        bf16x8 ah0 = *(const bf16x8*)&sH[m][kb * 32 + q * 8];
        bf16x8 ah1 = *(const bf16x8*)&sH[16 + m][kb * 32 + q * 8];
#pragma unroll
        for (int j = 0; j < 2; ++j) {
            bf16x8 b1v = *(const bf16x8*)(wl + (kb * 16 + 2 * wave + j) * 512);
            bf16x8 b2v = *(const bf16x8*)(wl + (kb * 16 + 2 * wave + 8 + j) * 512);
            aA[0][j] = __builtin_amdgcn_mfma_f32_16x16x32_bf16(ah0, b1v, aA[0][j], 0, 0, 0);
            aA[1][j] = __builtin_amdgcn_mfma_f32_16x16x32_bf16(ah1, b1v, aA[1][j], 0, 0, 0);
            aB[0][j] = __builtin_amdgcn_mfma_f32_16x16x32_bf16(ah0, b2v, aB[0][j], 0, 0, 0);
            aB[1][j] = __builtin_amdgcn_mfma_f32_16x16x32_bf16(ah1, b2v, aB[1][j], 0, 0, 0);
        }
    }
#pragma unroll
    for (int kb = 0; kb < 4; ++kb) {              // inv0*S-half of K
        u16x8 sv0 = *(const u16x8*)&sS[m][kb * 32 + q * 8];
        u16x8 sv1 = *(const u16x8*)&sS[16 + m][kb * 32 + q * 8];
        bf16x8 as0, as1;
#pragma unroll
        for (int j = 0; j < 8; ++j) {
            as0[j] = (short)f2bf(w0a * bf2f(sv0[j]));
            as1[j] = (short)f2bf(w0b * bf2f(sv1[j]));
        }
#pragma unroll
        for (int j = 0; j < 2; ++j) {
            bf16x8 b1v = *(const bf16x8*)(wl + ((kb + 4) * 16 + 2 * wave + j) * 512);
            bf16x8 b2v = *(const bf16x8*)(wl + ((kb + 4) * 16 + 2 * wave + 8 + j) * 512);
            aA[0][j] = __builtin_amdgcn_mfma_f32_16x16x32_bf16(as0, b1v, aA[0][j], 0, 0, 0);
            aA[1][j] = __builtin_amdgcn_mfma_f32_16x16x32_bf16(as1, b1v, aA[1][j], 0, 0, 0);
            aB[0][j] = __builtin_amdgcn_mfma_f32_16x16x32_bf16(as0, b2v, aB[0][j], 0, 0, 0);
            aB[1][j] = __builtin_amdgcn_mfma_f32_16x16x32_bf16(as1, b2v, aB[1][j], 0, 0, 0);
        }
    }
    __syncthreads();   // all ds_reads of sH/sS done before in-place epilogue overwrite

    // ---- epilogue: C layout row = rb + t*16 + q*4 + r, col = (2*wave+j)*16 + m ----
    float Rv[2];
#pragma unroll
    for (int j = 0; j < 2; ++j) Rv[j] = Rl[(2 * wave + j) * 16 + m];

#pragma unroll
    for (int t = 0; t < 2; ++t) {
#pragma unroll
        for (int r = 0; r < 4; ++r) {
            int rl = t * 16 + q * 4 + r;
            int gi = rb + rl;
            float wi0 = inv0[gi], wi2 = inv2[gi];
            int dgi = degi[gi];
#pragma unroll
            for (int j = 0; j < 2; ++j) {
                int cc = (2 * wave + j) * 16 + m;
                float z1 = aA[t][j][r], z2 = aB[t][j][r];
                float h = bf2f(sH[rl][cc]);
                float sva = bf2f(sS[rl][cc]);
                float ga = (z1 > 0.f ? z1 : 0.2f * z1) + 1.0f;
                float be = (z2 > 0.f ? z2 : 0.2f * z2);
                float mm = h + ga * Rv[j] + be - wi0 * sva;
                float hn = wi2 * (sva + h + mm);
                if (!last) {
                    sH[rl][cc] = f2bf(hn);     // in-place: this thread owns (rl,cc)
                } else if (dgi <= 5) {
                    float xv = bf2f(xb[(size_t)gi * DIM + cc]);
                    float t1 = bf2f(st1[(size_t)gi * 256 + cc]);
                    outp[(size_t)gi * DIM + cc] = 0.25f * (xv + t1 + h + hn);
                }
            }
        }
    }
    if (!last) {   // coalesced store of staged h_new into combined tail half
        __syncthreads();
        int g = lane >> 4, c = lane & 15;
#pragma unroll
        for (int it = 0; it < 2; ++it) {
            int rl = wave * 8 + it * 4 + g;
            ((u16x8*)stn)[(size_t)(rb + rl) * 32 + c] = *(u16x8*)&sH[rl][c * 8];
        }
    }
}

// ---------------- global kernels ----------------

// F0: shared hop 0 — gathers S(x); writes combined st1 = [t1 | h1].
__global__ __launch_bounds__(256, 4) void k_fused0(
    const unsigned short* __restrict__ xb, unsigned short* __restrict__ st1,
    const float* __restrict__ Rl, const short* __restrict__ Wp,
    const float* __restrict__ inv0, const float* __restrict__ inv1,
    const float* __restrict__ inv2,
    const int* __restrict__ rowptr, const int* __restrict__ degi,
    const int* __restrict__ col)
{
    __shared__ __align__(16) unsigned short sH[32][136], sS[32][136];
    int rb = blockIdx.x * 32;
    int wave = threadIdx.x >> 6, lane = threadIdx.x & 63;
    int g = lane >> 4, c = lane & 15;
#pragma unroll
    for (int it = 0; it < 2; ++it) {
        int rl = wave * 8 + it * 4 + g;
        int row = rb + rl;
        int start = rowptr[row], d = degi[row];
        u16x8 xv = ((const u16x8*)xb)[(size_t)row * 16 + c];
        float acc[8] = {0,0,0,0,0,0,0,0};
        gather4((const u16x8*)xb, col, start, d, lane, acc);
        u16x8 so;
#pragma unroll
        for (int j = 0; j < 8; ++j) so[j] = f2bf(acc[j]);
        *(u16x8*)&sS[rl][c * 8] = so;
        *(u16x8*)&sH[rl][c * 8] = xv;
        float w1 = inv1[row];   // head h1 = inv1*(S+x) -> st1 head half
        u16x8 ho;
#pragma unroll
        for (int j = 0; j < 8; ++j) ho[j] = f2bf(w1 * (acc[j] + bf2f(xv[j])));
        ((u16x8*)st1)[(size_t)row * 32 + 16 + c] = ho;
    }
    __syncthreads();
    tail_gemm32(rb, sH, sS, st1, st1, xb, (float*)0,
                Rl, Wp, inv0, inv2, degi, 0);
}

// Hop k: ONE gather pass over combined state (tail+head halves, shared indices,
// same 512B super-row). Head update direct; tail S/h staged -> GEMM + epilogue.
// final: head writes emb rows deg>5, tail epilogue writes rows deg<=5.
__global__ __launch_bounds__(256, 4) void k_hop(
    const unsigned short* __restrict__ st, unsigned short* __restrict__ stn,
    const unsigned short* __restrict__ st1,
    const unsigned short* __restrict__ xb, float* __restrict__ outp,
    const float* __restrict__ Rl, const short* __restrict__ Wp,
    const float* __restrict__ inv0, const float* __restrict__ inv1,
    const float* __restrict__ inv2,
    const int* __restrict__ rowptr, const int* __restrict__ degi,
    const int* __restrict__ col, int last)
{
    __shared__ __align__(16) unsigned short sH[32][136], sS[32][136];
    int rb = blockIdx.x * 32;
    int wave = threadIdx.x >> 6, lane = threadIdx.x & 63;
    int g = lane >> 4, c = lane & 15;

#pragma unroll
    for (int it = 0; it < 2; ++it) {
        int rl = wave * 8 + it * 4 + g;
        int row = rb + rl;
        int start = rowptr[row], d = degi[row];
        size_t ro = (size_t)row * 32 + c;
        u16x8 tv = ((const u16x8*)st)[ro];
        u16x8 hv = ((const u16x8*)st)[ro + 16];
        float accT[8] = {0,0,0,0,0,0,0,0};
        float accH[8] = {0,0,0,0,0,0,0,0};
        gather4_dualc((const u16x8*)st, col, start, d, lane, accT, accH);

        u16x8 so;
#pragma unroll
        for (int j = 0; j < 8; ++j) so[j] = f2bf(accT[j]);
        *(u16x8*)&sS[rl][c * 8] = so;
        *(u16x8*)&sH[rl][c * 8] = tv;

        float w1 = inv1[row];
        if (!last) {   // head h_next = inv1*(S_h + h) -> stn head half
            u16x8 ho;
#pragma unroll
            for (int j = 0; j < 8; ++j) ho[j] = f2bf(w1 * (accH[j] + bf2f(hv[j])));
            ((u16x8*)stn)[ro + 16] = ho;
        } else if (d > 5) {   // head final: emb = 0.25*(x+h1+h2+h3); h2=hv, h3=w1*(accH+hv)
            u16x8 xv = ((const u16x8*)xb)[(size_t)row * 16 + c];
            u16x8 h1 = ((const u16x8*)st1)[(size_t)row * 32 + 16 + c];
            f32x4 e0, e1;
#pragma unroll
            for (int j = 0; j < 4; ++j) {
                float h2 = bf2f(hv[j]);
                e0[j] = 0.25f * (bf2f(xv[j]) + bf2f(h1[j]) + h2 + w1 * (accH[j] + h2));
            }
#pragma unroll
            for (int j = 0; j < 4; ++j) {
                float h2 = bf2f(hv[4 + j]);
                e1[j] = 0.25f * (bf2f(xv[4 + j]) + bf2f(h1[4 + j]) + h2 + w1 * (accH[4 + j] + h2));
            }
            float* op = outp + (size_t)row * DIM + c * 8;
            *(f32x4*)op = e0;
            *(f32x4*)(op + 4) = e1;
        }
    }
    __syncthreads();

    tail_gemm32(rb, sH, sS, stn, st1, xb, outp,
                Rl, Wp, inv0, inv2, degi, last);
}

// ---------------- launch ----------------

extern "C" void kernel_launch(void* const* d_in, const int* in_sizes, int n_in,
                              void* d_out, int out_size, void* d_ws, size_t ws_size,
                              hipStream_t stream) {
    const float* x  = (const float*)d_in[0];
    const float* G1 = (const float*)d_in[1];
    const float* G2 = (const float*)d_in[2];
    const float* B1 = (const float*)d_in[3];
    const float* B2 = (const float*)d_in[4];
    const float* R  = (const float*)d_in[5];
    const int* esrc = (const int*)d_in[6];
    const int* edst = (const int*)d_in[7];
    float* out = (float*)d_out;

    char* base = (char*)d_ws;
    size_t off = 0;
    auto alloc = [&](size_t b) -> void* {
        void* p = base + off;
        off = (off + b + 255) & ~(size_t)255;
        return p;
    };
    int* degi   = (int*)alloc(4 * N_NODES);
    int* rowptr = (int*)alloc(4 * N_NODES);
    int* cnt    = (int*)alloc(4 * N_NODES);
    int* bsum   = (int*)alloc(4 * 256);
    int* col    = (int*)alloc(4 * N_EDGES);
    float* inv0 = (float*)alloc(4 * N_NODES);
    float* inv1 = (float*)alloc(4 * N_NODES);
    float* inv2 = (float*)alloc(4 * N_NODES);
    short* Wp   = (short*)alloc(2 * 3 * 65536);
    unsigned short* xb  = (unsigned short*)alloc(2ull * N_NODES * DIM);
    unsigned short* st1 = (unsigned short*)alloc(4ull * N_NODES * DIM);  // [t1|h1] super-rows
    unsigned short* st2 = (unsigned short*)alloc(4ull * N_NODES * DIM);  // [t2|h2] super-rows

    hipMemsetAsync(degi, 0, 4 * N_NODES, stream);
    k_degree<<<(N_EDGES + 255) / 256, 256, 0, stream>>>(esrc, degi);
    k_chunksum<<<NCHUNK, SCAN_B, 0, stream>>>(degi, bsum);
    k_rowptr<<<NCHUNK, SCAN_B, 0, stream>>>(degi, bsum, rowptr, cnt, inv0, inv1, inv2);
    k_fill<<<(N_EDGES + 255) / 256, 256, 0, stream>>>(esrc, edst, cnt, col);
    k_prep<<<768 + 12500, 256, 0, stream>>>(G1, G2, B1, B2, Wp, x, xb);

    // F0: shared hop 0 — one gather of S(x) -> st1 = [t1|h1]
    k_fused0<<<3125, 256, 0, stream>>>(xb, st1, R, Wp,
                                       inv0, inv1, inv2, rowptr, degi, col);

    // hop 1: combined gather st1 -> st2 (tail via GEMM, head direct)
    k_hop<<<3125, 256, 0, stream>>>(st1, st2, st1, xb, out,
                                    R + 128, Wp + 65536,
                                    inv0, inv1, inv2, rowptr, degi, col, 0);

    // hop 2 (final): head writes deg>5 rows, tail epilogue writes deg<=5 rows
    k_hop<<<3125, 256, 0, stream>>>(st2, (unsigned short*)0, st1, xb, out,
                                    R + 256, Wp + 131072,
                                    inv0, inv1, inv2, rowptr, degi, col, 1);
}

// Round 12
// 392.161 us; speedup vs baseline: 1.0302x; 1.0302x over previous
//
#include <hip/hip_runtime.h>

#define N_NODES 100000
#define N_EDGES 600000
#define DIM 128
#define SCAN_B 1024
#define NCHUNK 98   // ceil(100000/1024)

typedef __attribute__((ext_vector_type(4))) float f32x4;
typedef __attribute__((ext_vector_type(8))) short bf16x8;
typedef __attribute__((ext_vector_type(4))) unsigned short u16x4;
typedef __attribute__((ext_vector_type(8))) unsigned short u16x8;

__device__ __forceinline__ unsigned short f2bf(float f) {
    union { float f; unsigned u; } cv; cv.f = f;
    unsigned r = (cv.u + 0x7FFFu + ((cv.u >> 16) & 1u)) >> 16;
    return (unsigned short)r;
}
__device__ __forceinline__ float bf2f(unsigned short v) {
    union { unsigned u; float f; } c; c.u = ((unsigned)v) << 16; return c.f;
}

// ---------------- setup: degree / scan / csr fill / weight+x prep ----------------

__global__ void k_degree(const int* __restrict__ src, int* __restrict__ degi) {
    int e = blockIdx.x * 256 + threadIdx.x;
    if (e < N_EDGES) atomicAdd(&degi[src[e]], 1);
}

__global__ void k_chunksum(const int* __restrict__ degi, int* __restrict__ bsum) {
    __shared__ int sm[SCAN_B];
    int i = blockIdx.x * SCAN_B + threadIdx.x;
    sm[threadIdx.x] = (i < N_NODES) ? degi[i] : 0;
    __syncthreads();
    for (int s = SCAN_B / 2; s > 0; s >>= 1) {
        if (threadIdx.x < (unsigned)s) sm[threadIdx.x] += sm[threadIdx.x + s];
        __syncthreads();
    }
    if (threadIdx.x == 0) bsum[blockIdx.x] = sm[0];
}

// rowptr with FUSED chunk-prefix: each block reduces bsum[0..bid-1] itself (98 ints).
__global__ void k_rowptr(const int* __restrict__ degi, const int* __restrict__ bsum,
                         int* __restrict__ rowptr, int* __restrict__ cnt,
                         float* __restrict__ inv0, float* __restrict__ inv1,
                         float* __restrict__ inv2) {
    __shared__ int sm[SCAN_B];
    __shared__ int sb[128];
    int i = blockIdx.x * SCAN_B + threadIdx.x;
    int v = (i < N_NODES) ? degi[i] : 0;
    sm[threadIdx.x] = v;
    if (threadIdx.x < 128)
        sb[threadIdx.x] = (threadIdx.x < blockIdx.x) ? bsum[threadIdx.x] : 0;
    __syncthreads();
    for (int s = 1; s < SCAN_B; s <<= 1) {
        int a = (threadIdx.x >= (unsigned)s) ? sm[threadIdx.x - s] : 0;
        __syncthreads();
        sm[threadIdx.x] += a;
        __syncthreads();
    }
    for (int s = 64; s > 0; s >>= 1) {
        if (threadIdx.x < (unsigned)s) sb[threadIdx.x] += sb[threadIdx.x + s];
        __syncthreads();
    }
    if (i < N_NODES) {
        int excl = sb[0] + sm[threadIdx.x] - v;
        rowptr[i] = excl;
        cnt[i] = excl;
        float d = (float)v;
        inv0[i] = (v > 0) ? 1.0f / d : 0.0f;
        inv1[i] = 1.0f / (d + 1.0f);
        inv2[i] = 1.0f / (d + 2.0f);
    }
}

__global__ void k_fill(const int* __restrict__ src, const int* __restrict__ dst,
                       int* __restrict__ cnt, int* __restrict__ col) {
    int e = blockIdx.x * 256 + threadIdx.x;
    if (e < N_EDGES) {
        int pos = atomicAdd(&cnt[src[e]], 1);
        col[pos] = dst[e];
    }
}

// Merged prep: blocks [0,768) pack W -> Wp; blocks [768,13268) cast x -> bf16 xb.
// Wpack[l][kb(8)][nt(16)][lane(64)][j(8)] = W[k][n], k=kb*32+(lane>>4)*8+j, n=nt*16+(lane&15)
__global__ void k_prep(const float* __restrict__ G1, const float* __restrict__ G2,
                       const float* __restrict__ B1, const float* __restrict__ B2,
                       short* __restrict__ Wp,
                       const float* __restrict__ x, unsigned short* __restrict__ xb) {
    if (blockIdx.x < 768) {
        int idx = blockIdx.x * 256 + threadIdx.x;  // 3*65536 = 196608 total
        int j = idx & 7, lane = (idx >> 3) & 63, nt = (idx >> 9) & 15, kb = (idx >> 13) & 7, l = idx >> 16;
        int k = kb * 32 + (lane >> 4) * 8 + j;
        int n = nt * 16 + (lane & 15);
        float v;
        if (n < 128) {
            v = (k < 128) ? G1[(l * 128 + n) * 128 + k] : G2[(l * 128 + n) * 128 + (k - 128)];
        } else {
            int n2 = n - 128;
            v = (k < 128) ? B1[(l * 128 + n2) * 128 + k] : B2[(l * 128 + n2) * 128 + (k - 128)];
        }
        Wp[idx] = (short)f2bf(v);
    } else {
        int i = ((blockIdx.x - 768) * 256 + threadIdx.x) * 4;
        f32x4 v = *(const f32x4*)(x + i);
        unsigned short o0 = f2bf(v[0]), o1 = f2bf(v[1]), o2 = f2bf(v[2]), o3 = f2bf(v[3]);
        unsigned long long pk = (unsigned long long)o0 | ((unsigned long long)o1 << 16)
                              | ((unsigned long long)o2 << 32) | ((unsigned long long)o3 << 48);
        *(unsigned long long*)(xb + i) = pk;
    }
}

// ---------------- gathers ----------------
// lane = g*16 + c: sub-row g handles its row; c indexes 8-bf16 (16B) chunks.
// Loads batched-issued unconditionally (oob lanes read row 0), accumulate predicated.
// NOTE (R11 A/B): do NOT pin the batch live with opaque asm — forcing 16-deep
// batches raised HBM traffic (L2 thrash) and cost +8% at equal occupancy. The
// compiler's ~8-deep schedule is the measured optimum.

template <int NE>
__device__ __forceinline__ void gath_issue(const u16x8* __restrict__ h8,
        int idx, int base, int c, int d, float* acc) {
    u16x8 v[NE];
#pragma unroll
    for (int e = 0; e < NE; ++e) {
        int ce = __shfl(idx, base + e, 64);
        v[e] = h8[(size_t)ce * 16 + c];
    }
#pragma unroll
    for (int e = 0; e < NE; ++e) {
        if (e < d) {
#pragma unroll
            for (int j = 0; j < 8; ++j) acc[j] += bf2f(v[e][j]);
        }
    }
}

__device__ __forceinline__ void gather4(const u16x8* __restrict__ h8,
        const int* __restrict__ col, int start, int d, int lane, float* acc) {
    int c = lane & 15;
    int base = lane & 48;
    int dd = d < 16 ? d : 16;
    int idx = (c < dd) ? col[start + c] : 0;
    int dm = d;
    int tmx = __shfl_xor(dm, 16);
    dm = dm > tmx ? dm : tmx;
    tmx = __shfl_xor(dm, 32);
    dm = dm > tmx ? dm : tmx;
    if (dm <= 8) {
        gath_issue<8>(h8, idx, base, c, d, acc);
    } else {
        gath_issue<16>(h8, idx, base, c, d, acc);
        if (dm > 16) {
            for (int e = 16; e < d; ++e) {
                int c0 = col[start + e];
                u16x8 v = h8[(size_t)c0 * 16 + c];
#pragma unroll
                for (int j = 0; j < 8; ++j) acc[j] += bf2f(v[j]);
            }
        }
    }
}

// Combined super-row gather: st row = 512B = [tail 16 chunks | head 16 chunks].
template <int NE>
__device__ __forceinline__ void gath_issue2c(const u16x8* __restrict__ st8,
        int idx, int base, int c, int d, int e0, float* accT, float* accH) {
    u16x8 vT[NE], vH[NE];
#pragma unroll
    for (int e = 0; e < NE; ++e) {
        int ce = __shfl(idx, base + e0 + e, 64);
        size_t b = (size_t)ce * 32 + c;
        vT[e] = st8[b];
        vH[e] = st8[b + 16];
    }
#pragma unroll
    for (int e = 0; e < NE; ++e) {
        if (e0 + e < d) {
#pragma unroll
            for (int j = 0; j < 8; ++j) {
                accT[j] += bf2f(vT[e][j]);
                accH[j] += bf2f(vH[e][j]);
            }
        }
    }
}

__device__ __forceinline__ void gather4_dualc(const u16x8* __restrict__ st8,
        const int* __restrict__ col, int start, int d, int lane,
        float* accT, float* accH) {
    int c = lane & 15;
    int base = lane & 48;
    int dd = d < 16 ? d : 16;
    int idx = (c < dd) ? col[start + c] : 0;
    int dm = d;
    int tmx = __shfl_xor(dm, 16);
    dm = dm > tmx ? dm : tmx;
    tmx = __shfl_xor(dm, 32);
    dm = dm > tmx ? dm : tmx;
    if (dm <= 8) {
        gath_issue2c<8>(st8, idx, base, c, d, 0, accT, accH);
    } else {
        gath_issue2c<8>(st8, idx, base, c, d, 0, accT, accH);
        gath_issue2c<8>(st8, idx, base, c, d, 8, accT, accH);
        if (dm > 16) {
            for (int e = 16; e < d; ++e) {
                int c0 = col[start + e];
                size_t b = (size_t)c0 * 32 + c;
                u16x8 vT = st8[b];
                u16x8 vH = st8[b + 16];
#pragma unroll
                for (int j = 0; j < 8; ++j) {
                    accT[j] += bf2f(vT[j]);
                    accH[j] += bf2f(vH[j]);
                }
            }
        }
    }
}

// ---------------- tail GEMM phase, 32 rows per block ----------------
// Z = [h | inv0*S] @ Wl (256 cols), A from LDS, B from L1-hot Wp: wave w owns nt pairs
// {2w,2w+1} and {2w+8,2w+9}; each B fragment feeds both A-tiles.
// Epilogue output staged IN-PLACE into sH (bijective (row,col)<->thread map; barrier
// after the MFMA loop guarantees all ds_reads of sH complete before overwrite).
// m = h + gamma*R + beta - inv0*S;  h_new = inv2*(S + h + m)
// last: emb = 0.25*(x+t1+t2+t3) -> out rows with deg<=5 only (t1 = st1 tail half).
__device__ __forceinline__ void tail_gemm32(
    int rb,
    unsigned short (*sH)[136], unsigned short (*sS)[136],
    unsigned short* __restrict__ stn,       // combined next-state (tail half written here)
    const unsigned short* __restrict__ st1, // combined layer-1 state (t1 in tail half)
    const unsigned short* __restrict__ xb,
    float* __restrict__ outp,
    const float* __restrict__ Rl, const short* __restrict__ Wp,
    const float* __restrict__ inv0, const float* __restrict__ inv2,
    const int* __restrict__ degi, int last)
{
    int wave = threadIdx.x >> 6, lane = threadIdx.x & 63;
    int q = lane >> 4, m = lane & 15;
    float w0a = inv0[rb + m], w0b = inv0[rb + 16 + m];
    const short* wl = Wp + lane * 8;

    const f32x4 vz = {0.f, 0.f, 0.f, 0.f};
    f32x4 aA[2][2] = {{vz, vz}, {vz, vz}}, aB[2][2] = {{vz, vz}, {vz, vz}};

#pragma unroll
    for (int kb = 0; kb < 4; ++kb) {              // h-half of K
        bf16x8 ah0 = *(const bf16x8*)&sH[m][kb * 32 + q * 8];
        bf16x8 ah1 = *(const bf16x8*)&sH[16 + m][kb * 32 + q * 8];
#pragma unroll
        for (int j = 0; j < 2; ++j) {
            bf16x8 b1v = *(const bf16x8*)(wl + (kb * 16 + 2 * wave + j) * 512);
            bf16x8 b2v = *(const bf16x8*)(wl + (kb * 16 + 2 * wave + 8 + j) * 512);
            aA[0][j] = __builtin_amdgcn_mfma_f32_16x16x32_bf16(ah0, b1v, aA[0][j], 0, 0, 0);
            aA[1][j] = __builtin_amdgcn_mfma_f32_16x16x32_bf16(ah1, b1v, aA[1][j], 0, 0, 0);
            aB[0][j] = __builtin_amdgcn_mfma_f32_16x16x32_bf16(ah0, b2v, aB[0][j], 0, 0, 0);
            aB[1][j] = __builtin_amdgcn_mfma_f32_16x16x32_bf16(ah1, b2v, aB[1][j], 0, 0, 0);
        }
    }
#pragma unroll
    for (int kb = 0; kb < 4; ++kb) {              // inv0*S-half of K
        u16x8 sv0 = *(const u16x8*)&sS[m][kb * 32 + q * 8];
        u16x8 sv1 = *(const u16x8*)&sS[16 + m][kb * 32 + q * 8];
        bf16x8 as0, as1;
#pragma unroll
        for (int j = 0; j < 8; ++j) {
            as0[j] = (short)f2bf(w0a * bf2f(sv0[j]));
            as1[j] = (short)f2bf(w0b * bf2f(sv1[j]));
        }
#pragma unroll
        for (int j = 0; j < 2; ++j) {
            bf16x8 b1v = *(const bf16x8*)(wl + ((kb + 4) * 16 + 2 * wave + j) * 512);
            bf16x8 b2v = *(const bf16x8*)(wl + ((kb + 4) * 16 + 2 * wave + 8 + j) * 512);
            aA[0][j] = __builtin_amdgcn_mfma_f32_16x16x32_bf16(as0, b1v, aA[0][j], 0, 0, 0);
            aA[1][j] = __builtin_amdgcn_mfma_f32_16x16x32_bf16(as1, b1v, aA[1][j], 0, 0, 0);
            aB[0][j] = __builtin_amdgcn_mfma_f32_16x16x32_bf16(as0, b2v, aB[0][j], 0, 0, 0);
            aB[1][j] = __builtin_amdgcn_mfma_f32_16x16x32_bf16(as1, b2v, aB[1][j], 0, 0, 0);
        }
    }
    __syncthreads();   // all ds_reads of sH/sS done before in-place epilogue overwrite

    // ---- epilogue: C layout row = rb + t*16 + q*4 + r, col = (2*wave+j)*16 + m ----
    float Rv[2];
#pragma unroll
    for (int j = 0; j < 2; ++j) Rv[j] = Rl[(2 * wave + j) * 16 + m];

#pragma unroll
    for (int t = 0; t < 2; ++t) {
#pragma unroll
        for (int r = 0; r < 4; ++r) {
            int rl = t * 16 + q * 4 + r;
            int gi = rb + rl;
            float wi0 = inv0[gi], wi2 = inv2[gi];
            int dgi = degi[gi];
#pragma unroll
            for (int j = 0; j < 2; ++j) {
                int cc = (2 * wave + j) * 16 + m;
                float z1 = aA[t][j][r], z2 = aB[t][j][r];
                float h = bf2f(sH[rl][cc]);
                float sva = bf2f(sS[rl][cc]);
                float ga = (z1 > 0.f ? z1 : 0.2f * z1) + 1.0f;
                float be = (z2 > 0.f ? z2 : 0.2f * z2);
                float mm = h + ga * Rv[j] + be - wi0 * sva;
                float hn = wi2 * (sva + h + mm);
                if (!last) {
                    sH[rl][cc] = f2bf(hn);     // in-place: this thread owns (rl,cc)
                } else if (dgi <= 5) {
                    float xv = bf2f(xb[(size_t)gi * DIM + cc]);
                    float t1 = bf2f(st1[(size_t)gi * 256 + cc]);
                    outp[(size_t)gi * DIM + cc] = 0.25f * (xv + t1 + h + hn);
                }
            }
        }
    }
    if (!last) {   // coalesced store of staged h_new into combined tail half
        __syncthreads();
        int g = lane >> 4, c = lane & 15;
#pragma unroll
        for (int it = 0; it < 2; ++it) {
            int rl = wave * 8 + it * 4 + g;
            ((u16x8*)stn)[(size_t)(rb + rl) * 32 + c] = *(u16x8*)&sH[rl][c * 8];
        }
    }
}

// ---------------- global kernels ----------------

// F0: shared hop 0 — gathers S(x); writes combined st1 = [t1 | h1].
__global__ __launch_bounds__(256, 4) void k_fused0(
    const unsigned short* __restrict__ xb, unsigned short* __restrict__ st1,
    const float* __restrict__ Rl, const short* __restrict__ Wp,
    const float* __restrict__ inv0, const float* __restrict__ inv1,
    const float* __restrict__ inv2,
    const int* __restrict__ rowptr, const int* __restrict__ degi,
    const int* __restrict__ col)
{
    __shared__ __align__(16) unsigned short sH[32][136], sS[32][136];
    int rb = blockIdx.x * 32;
    int wave = threadIdx.x >> 6, lane = threadIdx.x & 63;
    int g = lane >> 4, c = lane & 15;
#pragma unroll
    for (int it = 0; it < 2; ++it) {
        int rl = wave * 8 + it * 4 + g;
        int row = rb + rl;
        int start = rowptr[row], d = degi[row];
        u16x8 xv = ((const u16x8*)xb)[(size_t)row * 16 + c];
        float acc[8] = {0,0,0,0,0,0,0,0};
        gather4((const u16x8*)xb, col, start, d, lane, acc);
        u16x8 so;
#pragma unroll
        for (int j = 0; j < 8; ++j) so[j] = f2bf(acc[j]);
        *(u16x8*)&sS[rl][c * 8] = so;
        *(u16x8*)&sH[rl][c * 8] = xv;
        float w1 = inv1[row];   // head h1 = inv1*(S+x) -> st1 head half
        u16x8 ho;
#pragma unroll
        for (int j = 0; j < 8; ++j) ho[j] = f2bf(w1 * (acc[j] + bf2f(xv[j])));
        ((u16x8*)st1)[(size_t)row * 32 + 16 + c] = ho;
    }
    __syncthreads();
    tail_gemm32(rb, sH, sS, st1, st1, xb, (float*)0,
                Rl, Wp, inv0, inv2, degi, 0);
}

// Hop k: ONE gather pass over combined state (tail+head halves, shared indices,
// same 512B super-row). Head update direct; tail S/h staged -> GEMM + epilogue.
// final: head writes emb rows deg>5, tail epilogue writes rows deg<=5.
__global__ __launch_bounds__(256, 4) void k_hop(
    const unsigned short* __restrict__ st, unsigned short* __restrict__ stn,
    const unsigned short* __restrict__ st1,
    const unsigned short* __restrict__ xb, float* __restrict__ outp,
    const float* __restrict__ Rl, const short* __restrict__ Wp,
    const float* __restrict__ inv0, const float* __restrict__ inv1,
    const float* __restrict__ inv2,
    const int* __restrict__ rowptr, const int* __restrict__ degi,
    const int* __restrict__ col, int last)
{
    __shared__ __align__(16) unsigned short sH[32][136], sS[32][136];
    int rb = blockIdx.x * 32;
    int wave = threadIdx.x >> 6, lane = threadIdx.x & 63;
    int g = lane >> 4, c = lane & 15;

#pragma unroll
    for (int it = 0; it < 2; ++it) {
        int rl = wave * 8 + it * 4 + g;
        int row = rb + rl;
        int start = rowptr[row], d = degi[row];
        size_t ro = (size_t)row * 32 + c;
        u16x8 tv = ((const u16x8*)st)[ro];
        u16x8 hv = ((const u16x8*)st)[ro + 16];
        float accT[8] = {0,0,0,0,0,0,0,0};
        float accH[8] = {0,0,0,0,0,0,0,0};
        gather4_dualc((const u16x8*)st, col, start, d, lane, accT, accH);

        u16x8 so;
#pragma unroll
        for (int j = 0; j < 8; ++j) so[j] = f2bf(accT[j]);
        *(u16x8*)&sS[rl][c * 8] = so;
        *(u16x8*)&sH[rl][c * 8] = tv;

        float w1 = inv1[row];
        if (!last) {   // head h_next = inv1*(S_h + h) -> stn head half
            u16x8 ho;
#pragma unroll
            for (int j = 0; j < 8; ++j) ho[j] = f2bf(w1 * (accH[j] + bf2f(hv[j])));
            ((u16x8*)stn)[ro + 16] = ho;
        } else if (d > 5) {   // head final: emb = 0.25*(x+h1+h2+h3); h2=hv, h3=w1*(accH+hv)
            u16x8 xv = ((const u16x8*)xb)[(size_t)row * 16 + c];
            u16x8 h1 = ((const u16x8*)st1)[(size_t)row * 32 + 16 + c];
            f32x4 e0, e1;
#pragma unroll
            for (int j = 0; j < 4; ++j) {
                float h2 = bf2f(hv[j]);
                e0[j] = 0.25f * (bf2f(xv[j]) + bf2f(h1[j]) + h2 + w1 * (accH[j] + h2));
            }
#pragma unroll
            for (int j = 0; j < 4; ++j) {
                float h2 = bf2f(hv[4 + j]);
                e1[j] = 0.25f * (bf2f(xv[4 + j]) + bf2f(h1[4 + j]) + h2 + w1 * (accH[4 + j] + h2));
            }
            float* op = outp + (size_t)row * DIM + c * 8;
            *(f32x4*)op = e0;
            *(f32x4*)(op + 4) = e1;
        }
    }
    __syncthreads();

    tail_gemm32(rb, sH, sS, stn, st1, xb, outp,
                Rl, Wp, inv0, inv2, degi, last);
}

// ---------------- launch ----------------

extern "C" void kernel_launch(void* const* d_in, const int* in_sizes, int n_in,
                              void* d_out, int out_size, void* d_ws, size_t ws_size,
                              hipStream_t stream) {
    const float* x  = (const float*)d_in[0];
    const float* G1 = (const float*)d_in[1];
    const float* G2 = (const float*)d_in[2];
    const float* B1 = (const float*)d_in[3];
    const float* B2 = (const float*)d_in[4];
    const float* R  = (const float*)d_in[5];
    const int* esrc = (const int*)d_in[6];
    const int* edst = (const int*)d_in[7];
    float* out = (float*)d_out;

    char* base = (char*)d_ws;
    size_t off = 0;
    auto alloc = [&](size_t b) -> void* {
        void* p = base + off;
        off = (off + b + 255) & ~(size_t)255;
        return p;
    };
    int* degi   = (int*)alloc(4 * N_NODES);
    int* rowptr = (int*)alloc(4 * N_NODES);
    int* cnt    = (int*)alloc(4 * N_NODES);
    int* bsum   = (int*)alloc(4 * 256);
    int* col    = (int*)alloc(4 * N_EDGES);
    float* inv0 = (float*)alloc(4 * N_NODES);
    float* inv1 = (float*)alloc(4 * N_NODES);
    float* inv2 = (float*)alloc(4 * N_NODES);
    short* Wp   = (short*)alloc(2 * 3 * 65536);
    unsigned short* xb  = (unsigned short*)alloc(2ull * N_NODES * DIM);
    unsigned short* st1 = (unsigned short*)alloc(4ull * N_NODES * DIM);  // [t1|h1] super-rows
    unsigned short* st2 = (unsigned short*)alloc(4ull * N_NODES * DIM);  // [t2|h2] super-rows

    hipMemsetAsync(degi, 0, 4 * N_NODES, stream);
    k_degree<<<(N_EDGES + 255) / 256, 256, 0, stream>>>(esrc, degi);
    k_chunksum<<<NCHUNK, SCAN_B, 0, stream>>>(degi, bsum);
    k_rowptr<<<NCHUNK, SCAN_B, 0, stream>>>(degi, bsum, rowptr, cnt, inv0, inv1, inv2);
    k_fill<<<(N_EDGES + 255) / 256, 256, 0, stream>>>(esrc, edst, cnt, col);
    k_prep<<<768 + 12500, 256, 0, stream>>>(G1, G2, B1, B2, Wp, x, xb);

    // F0: shared hop 0 — one gather of S(x) -> st1 = [t1|h1]
    k_fused0<<<3125, 256, 0, stream>>>(xb, st1, R, Wp,
                                       inv0, inv1, inv2, rowptr, degi, col);

    // hop 1: combined gather st1 -> st2 (tail via GEMM, head direct)
    k_hop<<<3125, 256, 0, stream>>>(st1, st2, st1, xb, out,
                                    R + 128, Wp + 65536,
                                    inv0, inv1, inv2, rowptr, degi, col, 0);

    // hop 2 (final): head writes deg>5 rows, tail epilogue writes deg<=5 rows
    k_hop<<<3125, 256, 0, stream>>>(st2, (unsigned short*)0, st1, xb, out,
                                    R + 256, Wp + 131072,
                                    inv0, inv1, inv2, rowptr, degi, col, 1);
}